// Round 10
// baseline (185.561 us; speedup 1.0000x reference)
//
#include <hip/hip_runtime.h>
#include <hip/hip_fp16.h>
#include <math.h>

#define Bn 16
#define Tn 2048
#define Fn 1025
#define KP 1056       // padded K = 33 * 32 (basisT row stride)
#define KROW 1064     // LDS u row stride in fp16
#define TR 4          // rows per tile
#define GRID 512
#define NT 16         // tiles per block: 8192 / 512
#define Dn 64
#define EPSF 1e-6f

typedef __attribute__((ext_vector_type(8))) _Float16 f16x8;
typedef __attribute__((ext_vector_type(4))) _Float16 f16x4;
typedef __attribute__((ext_vector_type(4))) float f32x4;

__device__ inline float waveReduceSum(float v) {
#pragma unroll
  for (int off = 32; off > 0; off >>= 1) v += __shfl_xor(v, off, 64);
  return v;
}

__device__ inline void gload16(const float* g, float* l) {
  __builtin_amdgcn_global_load_lds(
      (const __attribute__((address_space(1))) void*)(g),
      (__attribute__((address_space(3))) void*)(l), 16, 0, 0);
}

// ---------------- prep: basisT[d][k] fp16 (normalized), spacing outputs ----------------
__global__ __launch_bounds__(256) void prep_kernel(
    const float* __restrict__ freq, const float* __restrict__ spacing,
    _Float16* __restrict__ basisT, float* __restrict__ out2, float* __restrict__ out3) {
  __shared__ float wsum[4];
  const int d = blockIdx.x;
  const int tid = threadIdx.x;
  const float sp = fmaxf(spacing[d], 1e-6f);

  float pv[5];
  float lsum = 0.f;
#pragma unroll
  for (int it = 0; it < 5; ++it) {
    int f = tid + 256 * it;
    float p = 0.f;
    if (f < Fn) {
      double arg = 6.2831853071795864769 * (double)(freq[f] / sp);
      p = 0.5f * (1.0f + (float)cos(arg));
      lsum += p;
    }
    pv[it] = p;
  }
  float s = waveReduceSum(lsum);
  if ((tid & 63) == 0) wsum[tid >> 6] = s;
  __syncthreads();
  float inv = 1.0f / fmaxf((wsum[0] + wsum[1] + wsum[2] + wsum[3]) * (1.0f / 1025.0f), EPSF);

#pragma unroll
  for (int it = 0; it < 5; ++it) {
    int f = tid + 256 * it;
    if (f < KP) basisT[(size_t)d * KP + f] = (_Float16)(pv[it] * inv);
  }
  if (tid == 0) {
    out2[d] = spacing[d];
    out3[d] = 17150.0f / sp;
  }
}

// ---------------- fused pipelined: DMA-staged raw -> u -> MFMA -> epi ----------------
__global__ __launch_bounds__(256) void fused_kernel(
    const float* __restrict__ phase, const float* __restrict__ comb,
    const _Float16* __restrict__ basisT,
    const float* __restrict__ scalar, const float* __restrict__ obs_m,
    const float* __restrict__ rel_m, const float* __restrict__ stpacc,
    float* __restrict__ out0, float* __restrict__ out1) {
  __shared__ float rawS[2][3][TR][1024];    // 98304 B, DMA-filled, linear
  __shared__ _Float16 uLDS[TR * KROW];      // 8512 B
  __shared__ float cumS[TR * 5 * 65];       // 5200 B
  __shared__ float rowScale0[TR], rowScale1[TR];

  const int lane = threadIdx.x & 63;
  const int w = __builtin_amdgcn_readfirstlane(threadIdx.x >> 6);  // 0..3
  const int tile0 = blockIdx.x * NT;

  // MFMA geometry
  const int m16 = lane & 15;
  const int kg = lane >> 4;
  const int nh = w & 1;
  const int kh = w >> 1;
  const int d0 = nh * 32 + m16;
  const _Float16* ALp = uLDS + (size_t)(m16 & 3) * KROW + kg * 8;  // dup rows 4x
  const _Float16* B0 = basisT + (size_t)d0 * KP + kg * 8;
  const _Float16* B1 = basisT + (size_t)(d0 + 16) * KP + kg * 8;

  // ---- stage tile raw via global_load_lds (wave w stages its row), + 3 tail loads ----
  auto STAGE = [&](int tile, int buf, float* tl) {
    const int row = tile * TR + w;
    const int b = row >> 11;
    const int t = row & 2047;
    const float* pr = phase + (size_t)row * Fn;
    const float* c0 = comb + ((size_t)(b * 2 + 0) * Tn + t) * Fn;
    const float* c1 = comb + ((size_t)(b * 2 + 1) * Tn + t) * Fn;
#pragma unroll
    for (int c = 0; c < 4; ++c) {
      gload16(pr + (c * 64 + lane) * 4, &rawS[buf][0][w][c * 256]);
      gload16(c0 + (c * 64 + lane) * 4, &rawS[buf][1][w][c * 256]);
      gload16(c1 + (c * 64 + lane) * 4, &rawS[buf][2][w][c * 256]);
    }
    tl[0] = pr[1024]; tl[1] = c0[1024]; tl[2] = c1[1024];
  };

  // ---- build u (fp16) for the wave's row from staged raw ----
  auto U = [&](int buf, const float* tl, float* rowScale) {
    float4 pv[4], c0v[4], c1v[4];
#pragma unroll
    for (int it = 0; it < 4; ++it) {
      pv[it]  = *(const float4*)&rawS[buf][0][w][(lane + 64 * it) * 4];
      c0v[it] = *(const float4*)&rawS[buf][1][w][(lane + 64 * it) * 4];
      c1v[it] = *(const float4*)&rawS[buf][2][w][(lane + 64 * it) * 4];
    }
    float s = (lane == 0) ? tl[0] : 0.f;
#pragma unroll
    for (int it = 0; it < 4; ++it)
      s += pv[it].x + pv[it].y + pv[it].z + pv[it].w;
    s = waveReduceSum(s);
    const float mean_lm = s * (1.0f / 1025.0f);

    _Float16* urow = uLDS + (size_t)w * KROW;
    float su = 0.f;
#pragma unroll
    for (int it = 0; it < 4; ++it) {
      const float* pf = (const float*)&pv[it];
      const float* q0 = (const float*)&c0v[it];
      const float* q1 = (const float*)&c1v[it];
      f16x4 hv;
#pragma unroll
      for (int c2 = 0; c2 < 4; ++c2) {
        float tr = fmaxf(mean_lm - pf[c2], 0.f);
        float d1 = fabsf(q1[c2]) + 0.25f * fabsf(q0[c2]);
        float u = tr * (1.f + d1);
        su += u;
        hv[c2] = (_Float16)u;
      }
      *(f16x4*)(urow + (lane + 64 * it) * 4) = hv;
    }
    float u1024 = fmaxf(mean_lm - tl[0], 0.f) * (1.f + fabsf(tl[2]) + 0.25f * fabsf(tl[1]));
    if (lane == 0) su += u1024;
    if (lane < 32) urow[1024 + lane] = (lane == 0) ? (_Float16)u1024 : (_Float16)0.f;
    su = waveReduceSum(su);
    if (lane == 0) rowScale[w] = 1.0f / fmaxf(su * (1.0f / 1025.0f), EPSF);
  };

  // ---- MFMA phase: k split kh 0/1, n split nh 0/1; band snapshots; cum to LDS ----
  auto MFMAphase = [&]() {
    f32x4 acc0 = {0.f, 0.f, 0.f, 0.f};
    f32x4 acc1 = {0.f, 0.f, 0.f, 0.f};
    f32x4 s0a = acc0, s0b = acc0, s1a = acc0, s1b = acc0, s2a = acc0, s2b = acc0;

    auto loadA = [&](int kt) { return *(const f16x8*)(ALp + kt * 32); };
    auto tileA = [&](int kt, f16x8 a) {
      f16x8 b0 = *(const f16x8*)(B0 + kt * 32);
      f16x8 b1 = *(const f16x8*)(B1 + kt * 32);
      acc0 = __builtin_amdgcn_mfma_f32_16x16x32_f16(a, b0, acc0, 0, 0, 0);
      acc1 = __builtin_amdgcn_mfma_f32_16x16x32_f16(a, b1, acc1, 0, 0, 0);
    };
    auto boundary = [&](int kt, int KB, f32x4& sa, f32x4& sb) {
      f16x8 a = loadA(kt);
      const int kb = kt * 32 + kg * 8;
      f16x8 alo, ahi;
#pragma unroll
      for (int j = 0; j < 8; ++j) {
        bool lo = (kb + j) < KB;
        alo[j] = lo ? a[j] : (_Float16)0.f;
        ahi[j] = lo ? (_Float16)0.f : a[j];
      }
      tileA(kt, alo);
      sa = acc0; sb = acc1;
      tileA(kt, ahi);
    };
    auto stor = [&](int slot, const f32x4& v0, const f32x4& v1) {
      if (kg == 0) {
#pragma unroll
        for (int r = 0; r < 4; ++r) {
          cumS[(r * 5 + slot) * 65 + d0]      = v0[r];
          cumS[(r * 5 + slot) * 65 + d0 + 16] = v1[r];
        }
      }
    };

    if (kh == 0) {
      boundary(0, 22, s0a, s0b);
      tileA(1, loadA(1));
      boundary(2, 86, s1a, s1b);
#pragma unroll
      for (int kt = 3; kt < 10; ++kt) tileA(kt, loadA(kt));
      boundary(10, 342, s2a, s2b);
#pragma unroll
      for (int kt = 11; kt < 16; ++kt) tileA(kt, loadA(kt));
      stor(0, s0a, s0b);
      stor(1, s1a, s1b);
      stor(2, s2a, s2b);
      stor(3, acc0, acc1);
    } else {
#pragma unroll
      for (int kt = 16; kt < 33; ++kt) tileA(kt, loadA(kt));
      stor(4, acc0, acc1);
    }
  };

  // ---- epilogue for one tile: wave w -> row w ----
  auto EPI = [&](int tile, const float* rowScale) {
    const size_t bt = (size_t)(tile * TR + w);
    const float rs = rowScale[w];

    float sv = fmaxf(stpacc[bt * Dn + lane], 0.f);

    float q0 = cumS[(w * 5 + 0) * 65 + lane];
    float q1 = cumS[(w * 5 + 1) * 65 + lane];
    float q2 = cumS[(w * 5 + 2) * 65 + lane];
    float q3 = cumS[(w * 5 + 3) * 65 + lane] + cumS[(w * 5 + 4) * 65 + lane];
    float b0 = q0, b1 = q1 - q0, b2 = q2 - q1, b3 = q3 - q2;

    float ssum = waveReduceSum(sv);
    float stp = sv / fmaxf(ssum * (1.0f / 64.0f), EPSF);

    float4 scv = *(const float4*)(scalar + bt * 4);
    float4 om  = *(const float4*)(obs_m  + bt * 4);
    float4 rm  = *(const float4*)(rel_m  + bt * 4);
    float obs_q = (om.x + om.y + om.z + om.w) * 0.25f;
    float rel_q = (rm.x + rm.y + rm.z + rm.w) * 0.25f;
    float is_snd = fminf(fmaxf(scv.x, 0.f), 1.f);
    float rho = fabsf(fminf(fmaxf(scv.y, -1.f), 1.f));

    float c0 = q3 * rs * (1.0f / 1025.0f);
    float c1 = b0 * rs * (1.0f / 22.0f);
    float c2 = b1 * rs * (1.0f / 64.0f);
    float c3 = b2 * rs * (1.0f / 256.0f);
    float c4 = b3 * rs * (1.0f / 683.0f);

    float mean10 = (c0 + c1 + c2 + c3 + c4 + stp + obs_q + rel_q + is_snd + rho) * 0.1f;
    float logit = mean10 * (0.5f + 0.5f * is_snd);

    float2* op = (float2*)(out0 + (bt * Dn + lane) * 10);
    op[0] = make_float2(c0, c1);
    op[1] = make_float2(c2, c3);
    op[2] = make_float2(c4, stp);
    op[3] = make_float2(obs_q, rel_q);
    op[4] = make_float2(is_snd, rho);
    out1[bt * Dn + lane] = logit;
  };

  float tA[3], tB[3];

  // ---- prologue: stage tiles 0,1; build u(0) ----
  STAGE(tile0 + 0, 0, tA);
  STAGE(tile0 + 1, 1, tB);
  asm volatile("s_waitcnt vmcnt(15)" ::: "memory");   // tile 0 raw arrived
  __builtin_amdgcn_sched_barrier(0);
  U(0, tA, rowScale0);
  asm volatile("s_waitcnt lgkmcnt(0)" ::: "memory");
  __builtin_amdgcn_s_barrier();

  // iteration body: parity-static buffers (rule #20)
#define BODY(I, TS, TU, BS, BU, RSU, RSE)                       \
  MFMAphase();                                                   \
  STAGE(tile0 + ((I) + 2) % NT, BS, TS);                         \
  asm volatile("s_waitcnt lgkmcnt(0)" ::: "memory");             \
  __builtin_amdgcn_s_barrier();                                  \
  asm volatile("s_waitcnt vmcnt(15)" ::: "memory");              \
  __builtin_amdgcn_sched_barrier(0);                             \
  U(BU, TU, RSU);                                                \
  EPI(tile0 + (I), RSE);                                         \
  asm volatile("s_waitcnt lgkmcnt(0)" ::: "memory");             \
  __builtin_amdgcn_s_barrier();

#pragma unroll 1
  for (int ii = 0; ii < NT - 2; ii += 2) {
    BODY(ii,     tA, tB, 0, 1, rowScale1, rowScale0)   // even i
    BODY(ii + 1, tB, tA, 1, 0, rowScale0, rowScale1)   // odd i
  }
  BODY(NT - 2, tA, tB, 0, 1, rowScale1, rowScale0)     // i = 14 (even)
#undef BODY

  // ---- tail: tile NT-1 ----
  MFMAphase();
  asm volatile("s_waitcnt lgkmcnt(0)" ::: "memory");
  __builtin_amdgcn_s_barrier();
  asm volatile("s_waitcnt vmcnt(0)" ::: "memory");     // drain wrap-stage before exit
  EPI(tile0 + NT - 1, rowScale1);
}

extern "C" void kernel_launch(void* const* d_in, const int* in_sizes, int n_in,
                              void* d_out, int out_size, void* d_ws, size_t ws_size,
                              hipStream_t stream) {
  const float* phase   = (const float*)d_in[0];
  const float* comb    = (const float*)d_in[1];
  const float* scalar  = (const float*)d_in[2];
  const float* obs_m   = (const float*)d_in[3];
  const float* rel_m   = (const float*)d_in[4];
  const float* stpacc  = (const float*)d_in[5];
  const float* freq    = (const float*)d_in[6];
  const float* spacing = (const float*)d_in[7];

  float* out  = (float*)d_out;
  float* out0 = out;                                    // (B,T,D,10)
  float* out1 = out + (size_t)Bn * Tn * Dn * 10;        // (B,T,D)
  float* out2 = out1 + (size_t)Bn * Tn * Dn;            // (D,)
  float* out3 = out2 + Dn;                              // (D,)

  _Float16* basisT = (_Float16*)d_ws;                   // 64*KP fp16 = 135 KB

  prep_kernel<<<Dn, 256, 0, stream>>>(freq, spacing, basisT, out2, out3);
  fused_kernel<<<GRID, 256, 0, stream>>>(
      phase, comb, basisT, scalar, obs_m, rel_m, stpacc, out0, out1);
}

// Round 11
// 118.602 us; speedup vs baseline: 1.5646x; 1.5646x over previous
//
#include <hip/hip_runtime.h>
#include <hip/hip_fp16.h>
#include <math.h>

#define Bn 16
#define Tn 2048
#define Fn 1025
#define KP 1056       // padded K = 33 * 32 (basisT row stride)
#define KROW 1064     // LDS u row stride in fp16 (2128 B -> 20 mod 32 banks, 2-way = free)
#define ROWS 16       // rows per block; 8 waves -> 2 rows/wave
#define NSLOT 7       // q0..q3, s22, s86, s342partial
#define Dn 64
#define EPSF 1e-6f

typedef __attribute__((ext_vector_type(8))) _Float16 f16x8;
typedef __attribute__((ext_vector_type(4))) _Float16 f16x4;
typedef __attribute__((ext_vector_type(4))) float f32x4;

__device__ inline float waveReduceSum(float v) {
#pragma unroll
  for (int off = 32; off > 0; off >>= 1) v += __shfl_xor(v, off, 64);
  return v;
}

// ---------------- prep: basisT[d][k] fp16 (normalized), spacing outputs ----------------
__global__ __launch_bounds__(256) void prep_kernel(
    const float* __restrict__ freq, const float* __restrict__ spacing,
    _Float16* __restrict__ basisT, float* __restrict__ out2, float* __restrict__ out3) {
  __shared__ float wsum[4];
  const int d = blockIdx.x;
  const int tid = threadIdx.x;
  const float sp = fmaxf(spacing[d], 1e-6f);

  float pv[5];
  float lsum = 0.f;
#pragma unroll
  for (int it = 0; it < 5; ++it) {
    int f = tid + 256 * it;
    float p = 0.f;
    if (f < Fn) {
      double arg = 6.2831853071795864769 * (double)(freq[f] / sp);
      p = 0.5f * (1.0f + (float)cos(arg));
      lsum += p;
    }
    pv[it] = p;
  }
  float s = waveReduceSum(lsum);
  if ((tid & 63) == 0) wsum[tid >> 6] = s;
  __syncthreads();
  float inv = 1.0f / fmaxf((wsum[0] + wsum[1] + wsum[2] + wsum[3]) * (1.0f / 1025.0f), EPSF);

#pragma unroll
  for (int it = 0; it < 5; ++it) {
    int f = tid + 256 * it;
    if (f < KP) basisT[(size_t)d * KP + f] = (_Float16)(pv[it] * inv);
  }
  if (tid == 0) {
    out2[d] = spacing[d];
    out3[d] = 17150.0f / sp;
  }
}

// ---------------- fused: 8 waves, 2 rows/wave, k-quarter MFMA ----------------
__global__ __launch_bounds__(512) void fused_kernel(
    const float* __restrict__ phase, const float* __restrict__ comb,
    const _Float16* __restrict__ basisT,
    const float* __restrict__ scalar, const float* __restrict__ obs_m,
    const float* __restrict__ rel_m, const float* __restrict__ stpacc,
    float* __restrict__ out0, float* __restrict__ out1) {
  __shared__ _Float16 uLDS[ROWS * KROW];            // 34048 B
  __shared__ float cumS[ROWS * NSLOT * 65];         // 29120 B
  __shared__ float rowScale[ROWS];

  const int lane = threadIdx.x & 63;
  const int w = __builtin_amdgcn_readfirstlane(threadIdx.x >> 6);  // 0..7
  const int row0 = blockIdx.x * ROWS;

  // ---- Phase 1: wave w -> rows 2w, 2w+1 (chain length 2) ----
#pragma unroll 1
  for (int k2 = 0; k2 < 2; ++k2) {
    const int rl = 2 * w + k2;
    const int row = row0 + rl;
    const int b = row >> 11;
    const int t = row & 2047;
    const float* prow  = phase + (size_t)row * Fn;
    const float* c0row = comb + ((size_t)(b * 2 + 0) * Tn + t) * Fn;
    const float* c1row = comb + ((size_t)(b * 2 + 1) * Tn + t) * Fn;

    float4 pv[5], c0v[5], c1v[5];
#pragma unroll
    for (int it = 0; it < 5; ++it) {
      const int i = lane + 64 * it;
      if (i < 256) {
        pv[it]  = *(const float4*)(prow  + 4 * i);
        c0v[it] = *(const float4*)(c0row + 4 * i);
        c1v[it] = *(const float4*)(c1row + 4 * i);
      } else if (i == 256) {
        pv[it]  = make_float4(prow[1024],  0.f, 0.f, 0.f);
        c0v[it] = make_float4(c0row[1024], 0.f, 0.f, 0.f);
        c1v[it] = make_float4(c1row[1024], 0.f, 0.f, 0.f);
      } else {
        pv[it]  = make_float4(0.f, 0.f, 0.f, 0.f);
        c0v[it] = make_float4(0.f, 0.f, 0.f, 0.f);
        c1v[it] = make_float4(0.f, 0.f, 0.f, 0.f);
      }
    }

    float s = 0.f;
#pragma unroll
    for (int it = 0; it < 5; ++it)
      s += pv[it].x + pv[it].y + pv[it].z + pv[it].w;
    s = waveReduceSum(s);
    const float mean_lm = s * (1.0f / 1025.0f);

    _Float16* urow = uLDS + (size_t)rl * KROW;
    float su = 0.f;
#pragma unroll
    for (int it = 0; it < 5; ++it) {
      const int i = lane + 64 * it;
      float4 u;
      const float* pf = (const float*)&pv[it];
      const float* q0 = (const float*)&c0v[it];
      const float* q1 = (const float*)&c1v[it];
      float* uf = (float*)&u;
#pragma unroll
      for (int c2 = 0; c2 < 4; ++c2) {
        float tr = fmaxf(mean_lm - pf[c2], 0.f);
        float d1 = fabsf(q1[c2]) + 0.25f * fabsf(q0[c2]);
        uf[c2] = tr * (1.f + d1);
      }
      if (i > 256) { u.x = 0.f; u.y = 0.f; u.z = 0.f; u.w = 0.f; }
      else if (i == 256) { u.y = 0.f; u.z = 0.f; u.w = 0.f; }
      su += u.x + u.y + u.z + u.w;
      if (i < 264) {                       // quads 257..263 store zeros (k tail)
        f16x4 hv;
#pragma unroll
        for (int c2 = 0; c2 < 4; ++c2) hv[c2] = (_Float16)uf[c2];
        *(f16x4*)(urow + 4 * i) = hv;
      }
    }
    su = waveReduceSum(su);
    if (lane == 0) rowScale[rl] = 1.0f / fmaxf(su * (1.0f / 1025.0f), EPSF);
  }
  __syncthreads();

  // ---- Phase 2: MFMA. wave = (kq = w>>1 in 0..3, nh = w&1); 16 real rows ----
  const int m16 = lane & 15;
  const int kg = lane >> 4;
  const int nh = w & 1;
  const int kq = w >> 1;
  const int d0 = nh * 32 + m16;

  const _Float16* ALp = uLDS + (size_t)m16 * KROW + kg * 8;
  const _Float16* B0 = basisT + (size_t)d0 * KP + kg * 8;
  const _Float16* B1 = basisT + (size_t)(d0 + 16) * KP + kg * 8;

  f32x4 acc0 = {0.f, 0.f, 0.f, 0.f};
  f32x4 acc1 = {0.f, 0.f, 0.f, 0.f};

  auto loadA = [&](int kt) { return *(const f16x8*)(ALp + kt * 32); };
  auto tileA = [&](int kt, f16x8 a) {
    f16x8 b0 = *(const f16x8*)(B0 + kt * 32);
    f16x8 b1 = *(const f16x8*)(B1 + kt * 32);
    acc0 = __builtin_amdgcn_mfma_f32_16x16x32_f16(a, b0, acc0, 0, 0, 0);
    acc1 = __builtin_amdgcn_mfma_f32_16x16x32_f16(a, b1, acc1, 0, 0, 0);
  };
  auto stor = [&](int slot, const f32x4& v0, const f32x4& v1) {
#pragma unroll
    for (int r = 0; r < 4; ++r) {
      const int rr = kg * 4 + r;
      cumS[(rr * NSLOT + slot) * 65 + d0]      = v0[r];
      cumS[(rr * NSLOT + slot) * 65 + d0 + 16] = v1[r];
    }
  };
  auto boundary = [&](int kt, int KB, f32x4& sa, f32x4& sb) {
    f16x8 a = loadA(kt);
    const int kb = kt * 32 + kg * 8;
    f16x8 alo, ahi;
#pragma unroll
    for (int j = 0; j < 8; ++j) {
      bool lo = (kb + j) < KB;
      alo[j] = lo ? a[j] : (_Float16)0.f;
      ahi[j] = lo ? (_Float16)0.f : a[j];
    }
    tileA(kt, alo);
    sa = acc0; sb = acc1;
    tileA(kt, ahi);
  };

  if (kq == 0) {
    f32x4 za = {0.f, 0.f, 0.f, 0.f};
    f32x4 s22a = za, s22b = za, s86a = za, s86b = za;
    boundary(0, 22, s22a, s22b);             // band0 boundary k=22 (kt0)
    tileA(1, loadA(1));
    boundary(2, 86, s86a, s86b);             // band1 boundary k=86 (kt2)
#pragma unroll
    for (int kt = 3; kt < 8; ++kt) tileA(kt, loadA(kt));
    stor(0, acc0, acc1);                     // q0 = kt0..7
    stor(4, s22a, s22b);                     // cum to k=22
    stor(5, s86a, s86b);                     // cum to k=86
  } else if (kq == 1) {
    f32x4 za = {0.f, 0.f, 0.f, 0.f};
    f32x4 s342a = za, s342b = za;
    tileA(8, loadA(8));
    tileA(9, loadA(9));
    boundary(10, 342, s342a, s342b);         // band2 boundary k=342 (kt10)
#pragma unroll
    for (int kt = 11; kt < 17; ++kt) tileA(kt, loadA(kt));
    stor(1, acc0, acc1);                     // q1 = kt8..16
    stor(6, s342a, s342b);                   // kq1 partial to k=342
  } else if (kq == 2) {
#pragma unroll
    for (int kt = 17; kt < 25; ++kt) tileA(kt, loadA(kt));
    stor(2, acc0, acc1);                     // q2 = kt17..24
  } else {
#pragma unroll
    for (int kt = 25; kt < 33; ++kt) tileA(kt, loadA(kt));
    stor(3, acc0, acc1);                     // q3 = kt25..32
  }
  __syncthreads();

  // ---- Phase 3: epilogue. wave w -> rows 2w, 2w+1; lane = d ----
#pragma unroll
  for (int k2 = 0; k2 < 2; ++k2) {
    const int rl = 2 * w + k2;
    const size_t bt = (size_t)(row0 + rl);
    const float rs = rowScale[rl];

    float sv = fmaxf(stpacc[bt * Dn + lane], 0.f);   // issue early

    float q[NSLOT];
#pragma unroll
    for (int s2 = 0; s2 < NSLOT; ++s2)
      q[s2] = cumS[(rl * NSLOT + s2) * 65 + lane];

    float total = q[0] + q[1] + q[2] + q[3];
    float cum342 = q[0] + q[6];

    float ssum = waveReduceSum(sv);
    float stp = sv / fmaxf(ssum * (1.0f / 64.0f), EPSF);

    float4 scv = *(const float4*)(scalar + bt * 4);
    float4 om  = *(const float4*)(obs_m  + bt * 4);
    float4 rm  = *(const float4*)(rel_m  + bt * 4);
    float obs_q = (om.x + om.y + om.z + om.w) * 0.25f;
    float rel_q = (rm.x + rm.y + rm.z + rm.w) * 0.25f;
    float is_snd = fminf(fmaxf(scv.x, 0.f), 1.f);
    float rho = fabsf(fminf(fmaxf(scv.y, -1.f), 1.f));

    float c0 = total * rs * (1.0f / 1025.0f);
    float c1 = q[4] * rs * (1.0f / 22.0f);
    float c2 = (q[5] - q[4]) * rs * (1.0f / 64.0f);
    float c3 = (cum342 - q[5]) * rs * (1.0f / 256.0f);
    float c4 = (total - cum342) * rs * (1.0f / 683.0f);

    float mean10 = (c0 + c1 + c2 + c3 + c4 + stp + obs_q + rel_q + is_snd + rho) * 0.1f;
    float logit = mean10 * (0.5f + 0.5f * is_snd);

    float2* op = (float2*)(out0 + (bt * Dn + lane) * 10);
    op[0] = make_float2(c0, c1);
    op[1] = make_float2(c2, c3);
    op[2] = make_float2(c4, stp);
    op[3] = make_float2(obs_q, rel_q);
    op[4] = make_float2(is_snd, rho);
    out1[bt * Dn + lane] = logit;
  }
}

extern "C" void kernel_launch(void* const* d_in, const int* in_sizes, int n_in,
                              void* d_out, int out_size, void* d_ws, size_t ws_size,
                              hipStream_t stream) {
  const float* phase   = (const float*)d_in[0];
  const float* comb    = (const float*)d_in[1];
  const float* scalar  = (const float*)d_in[2];
  const float* obs_m   = (const float*)d_in[3];
  const float* rel_m   = (const float*)d_in[4];
  const float* stpacc  = (const float*)d_in[5];
  const float* freq    = (const float*)d_in[6];
  const float* spacing = (const float*)d_in[7];

  float* out  = (float*)d_out;
  float* out0 = out;                                    // (B,T,D,10)
  float* out1 = out + (size_t)Bn * Tn * Dn * 10;        // (B,T,D)
  float* out2 = out1 + (size_t)Bn * Tn * Dn;            // (D,)
  float* out3 = out2 + Dn;                              // (D,)

  _Float16* basisT = (_Float16*)d_ws;                   // 64*KP fp16 = 135 KB

  prep_kernel<<<Dn, 256, 0, stream>>>(freq, spacing, basisT, out2, out3);
  fused_kernel<<<Bn * Tn / ROWS, 512, 0, stream>>>(
      phase, comb, basisT, scalar, obs_m, rel_m, stpacc, out0, out1);
}